// Round 3
// baseline (28.636 us; speedup 1.0000x reference)
//
#include <hip/hip_runtime.h>

// PROBE ROUND: identical math to R2, but the kernel is launched TWICE in the
// graph. dur(2x) - dur(1x) = true kernel time, cancelling fixed launch/graph
// overhead. Second launch is idempotent (same inputs -> same output).
//
// out[i] = P(x[i]) / (|x[i]*Q(x[i])| + 1), packed Horner in v2f {num,den}.

typedef float v2f __attribute__((ext_vector_type(2)));

#define EPT 8  // elements per thread

__global__ __launch_bounds__(256) void rationals_kernel(
    const float* __restrict__ x,
    const float* __restrict__ coeff,
    float* __restrict__ out, int N) {
    int idx = (blockIdx.x * blockDim.x + threadIdx.x) * EPT;
    if (idx >= N) return;

    float xs[EPT];
    float4 xa = *reinterpret_cast<const float4*>(x + idx);
    float4 xb = *reinterpret_cast<const float4*>(x + idx + 4);
    xs[0] = xa.x; xs[1] = xa.y; xs[2] = xa.z; xs[3] = xa.w;
    xs[4] = xb.x; xs[5] = xb.y; xs[6] = xb.z; xs[7] = xb.w;

    v2f xx[EPT], h[EPT];
    float cn_top = coeff[63];
    float cd_top = coeff[127];
#pragma unroll
    for (int j = 0; j < EPT; ++j) {
        xx[j] = (v2f){xs[j], xs[j]};
        h[j]  = (v2f){cn_top, cd_top};
    }

#pragma unroll
    for (int p = 62; p >= 0; --p) {
        v2f c2 = {coeff[p], coeff[64 + p]};  // wave-uniform pair
#pragma unroll
        for (int j = 0; j < EPT; ++j)
            h[j] = __builtin_elementwise_fma(h[j], xx[j], c2);
    }

    float o[EPT];
#pragma unroll
    for (int j = 0; j < EPT; ++j) {
        float den = h[j].y * xs[j];          // exponents 1..64
        o[j] = h[j].x * __builtin_amdgcn_rcpf(fabsf(den) + 1.0f);
    }
    *reinterpret_cast<float4*>(out + idx)     = (float4){o[0], o[1], o[2], o[3]};
    *reinterpret_cast<float4*>(out + idx + 4) = (float4){o[4], o[5], o[6], o[7]};
}

extern "C" void kernel_launch(void* const* d_in, const int* in_sizes, int n_in,
                              void* d_out, int out_size, void* d_ws, size_t ws_size,
                              hipStream_t stream) {
    const float* x     = (const float*)d_in[0];
    const float* coeff = (const float*)d_in[1];
    float* out = (float*)d_out;
    int N = in_sizes[0];  // 4194304, divisible by EPT

    int threads = 256;
    int elems_per_block = threads * EPT;
    int blocks = (N + elems_per_block - 1) / elems_per_block;  // 2048

    // Launch TWICE: overhead-cancellation probe (idempotent).
    rationals_kernel<<<blocks, threads, 0, stream>>>(x, coeff, out, N);
    rationals_kernel<<<blocks, threads, 0, stream>>>(x, coeff, out, N);
}

// Round 4
// 20.436 us; speedup vs baseline: 1.4012x; 1.4012x over previous
//
#include <hip/hip_runtime.h>

// out[i] = P(x[i]) / (|x[i]*Q(x[i])| + 1)
// Two-pass scalar-FMA Horner:
//   pass 1: num = Horner(coeff[0..63])   -- 64 coeffs SGPR-resident
//   pass 2: den = x * Horner(coeff[64..127])
// Each Horner step is v_fma_f32 v_h, v_h, v_x, s_c (2 VGPR reads + SGPR
// coefficient via scalar bus) -- testing the RF-port-limit theory that
// 3-VGPR-operand FMAs issue at 2/3 rate (103 TF) vs 2-read at 157 TF.
// EPT=16 independent chains for ILP; rcp instead of precise div
// (den >= 1, rel err ~1e-6, threshold 0.4275).

#define EPT 16  // elements per thread

__global__ __launch_bounds__(256) void rationals_kernel(
    const float* __restrict__ x,
    const float* __restrict__ coeff,
    float* __restrict__ out, int N) {
    int idx = (blockIdx.x * blockDim.x + threadIdx.x) * EPT;
    if (idx >= N) return;

    float xs[EPT];
#pragma unroll
    for (int j = 0; j < EPT; j += 4) {
        float4 v = *reinterpret_cast<const float4*>(x + idx + j);
        xs[j] = v.x; xs[j + 1] = v.y; xs[j + 2] = v.z; xs[j + 3] = v.w;
    }

    // Pass 1: numerator polynomial, coefficients 0..63
    float num[EPT];
    {
        float c = coeff[63];
#pragma unroll
        for (int j = 0; j < EPT; ++j) num[j] = c;
#pragma unroll
        for (int p = 62; p >= 0; --p) {
            c = coeff[p];
#pragma unroll
            for (int j = 0; j < EPT; ++j)
                num[j] = fmaf(num[j], xs[j], c);
        }
    }

    // Pass 2: denominator polynomial, coefficients 64..127 (exponents 1..64)
    float den[EPT];
    {
        float c = coeff[127];
#pragma unroll
        for (int j = 0; j < EPT; ++j) den[j] = c;
#pragma unroll
        for (int p = 126; p >= 64; --p) {
            c = coeff[p];
#pragma unroll
            for (int j = 0; j < EPT; ++j)
                den[j] = fmaf(den[j], xs[j], c);
        }
    }

    float o[EPT];
#pragma unroll
    for (int j = 0; j < EPT; ++j) {
        float d = den[j] * xs[j];
        o[j] = num[j] * __builtin_amdgcn_rcpf(fabsf(d) + 1.0f);
    }
#pragma unroll
    for (int j = 0; j < EPT; j += 4)
        *reinterpret_cast<float4*>(out + idx + j) =
            (float4){o[j], o[j + 1], o[j + 2], o[j + 3]};
}

extern "C" void kernel_launch(void* const* d_in, const int* in_sizes, int n_in,
                              void* d_out, int out_size, void* d_ws, size_t ws_size,
                              hipStream_t stream) {
    const float* x     = (const float*)d_in[0];
    const float* coeff = (const float*)d_in[1];
    float* out = (float*)d_out;
    int N = in_sizes[0];  // 4194304, divisible by EPT

    int threads = 256;
    int elems_per_block = threads * EPT;
    int blocks = (N + elems_per_block - 1) / elems_per_block;  // 1024
    rationals_kernel<<<blocks, threads, 0, stream>>>(x, coeff, out, N);
}